// Round 9
// baseline (327.815 us; speedup 1.0000x reference)
//
#include <hip/hip_runtime.h>

typedef unsigned int uint;
typedef unsigned short ushort;

#define B_  2
#define NA  2048
#define NN  48
#define G_  50
#define F_  128
#define NK  49   // Nn + 1 (self)
#define NROW (B_ * NA * NN)   // 196608 flat filter rows
#define NAT  (B_ * NA)        // 4096 atoms

typedef short short8 __attribute__((ext_vector_type(8)));
typedef float floatx4 __attribute__((ext_vector_type(4)));

__device__ __forceinline__ float ssp(float z) {  // softplus(z)-ln2: fast v_exp/v_log
  return fmaxf(z, 0.f) + __logf(1.f + __expf(-fabsf(z))) - 0.69314718055994531f;
}
__device__ __forceinline__ ushort f2bf(float x) {  // RNE
  union { float f; uint u; } v; v.f = x;
  uint u = v.u;
  u += 0x7fffu + ((u >> 16) & 1u);
  return (ushort)(u >> 16);
}
__device__ __forceinline__ uint pk2bf(float x, float y) {
  return (uint)f2bf(x) | ((uint)f2bf(y) << 16);
}

// =====================================================================
// P: weight prep -> transposed bf16 [n][k] tables (MFMA B-fragments)
//    for filter (Wf1,Wf2), V and O paths. Q/K stay f32.
// =====================================================================
extern "C" __global__ __launch_bounds__(256)
void prep_kernel(const float* __restrict__ Wf1, const float* __restrict__ Wf2,
                 const float* __restrict__ Wv, const float* __restrict__ Wo,
                 ushort* __restrict__ Wf1t, ushort* __restrict__ Wf2t,
                 ushort* __restrict__ Wvt, ushort* __restrict__ Wot)
{
  int gid = blockIdx.x * 256 + threadIdx.x;   // 24576 threads
  if (gid < 8192) {   // Wf1t [128][64], K padded 50->64
    int n = gid >> 6, k = gid & 63;
    Wf1t[gid] = f2bf((k < G_) ? Wf1[(size_t)k * F_ + n] : 0.f);
  }
  for (int idx = gid; idx < 3 * 16384; idx += 24576) {
    int m = idx >> 14, e = idx & 16383;
    int n = e >> 7, k = e & 127;
    const float* src = (m == 0) ? Wf2 : (m == 1) ? Wv : Wo;
    ushort* dst = (m == 0) ? Wf2t : (m == 1) ? Wvt : Wot;
    dst[e] = f2bf(src[(size_t)k * F_ + n]);
  }
}

// =====================================================================
// K0a: Q/K = x @ {Wq,Wk} in f32 VALU (R5/R6-proven structure).
// =====================================================================
extern "C" __global__ __launch_bounds__(256, 4)
void qk_kernel(const float* __restrict__ x,
               const float* __restrict__ Wq, const float* __restrict__ Wk,
               float* __restrict__ Qo, float* __restrict__ Ko)
{
  __shared__ float xs[32 * 128];
  const int t = threadIdx.x;
  const int f = t & 127, h = t >> 7;
  const size_t Rb = (size_t)blockIdx.x * 32;
  const float* W = blockIdx.y ? Wk : Wq;
  float* O = blockIdx.y ? Ko : Qo;

  {
    const float4* src = (const float4*)(x + Rb * F_);
    float4* dst = (float4*)xs;
    #pragma unroll
    for (int k = 0; k < 4; ++k) dst[t + 256 * k] = src[t + 256 * k];
  }
  __syncthreads();

  float acc[16];
  #pragma unroll
  for (int j = 0; j < 16; ++j) acc[j] = 0.f;
  #pragma unroll
  for (int kc = 0; kc < 4; ++kc) {
    float wr[32];
    #pragma unroll
    for (int kk = 0; kk < 32; ++kk) wr[kk] = W[(size_t)(kc * 32 + kk) * F_ + f];
    #pragma unroll
    for (int j = 0; j < 16; ++j) {
      const float4* xr = (const float4*)&xs[(h * 16 + j) * 128 + kc * 32];
      #pragma unroll
      for (int qq = 0; qq < 8; ++qq) {   // wave-uniform b128 broadcasts
        float4 v = xr[qq];
        acc[j] += v.x * wr[qq * 4] + v.y * wr[qq * 4 + 1]
                + v.z * wr[qq * 4 + 2] + v.w * wr[qq * 4 + 3];
      }
    }
  }
  #pragma unroll
  for (int j = 0; j < 16; ++j)
    O[(Rb + h * 16 + j) * F_ + f] = acc[j];
}

// =====================================================================
// K0b: V = x @ Wv via bf16 MFMA — operand-swapped (weights as A):
//   thread holds 4 consecutive n -> float4 stores. (R2-verified, kept.)
// =====================================================================
extern "C" __global__ __launch_bounds__(256, 4)
void v_kernel(const float* __restrict__ x, const ushort* __restrict__ Wvt,
              float* __restrict__ Vo)
{
  __shared__ ushort xb[16 * 136];   // row stride 272 B
  const int t = threadIdx.x;
  const int lane = t & 63, w = t >> 6;
  const int c16 = lane & 15, q = lane >> 4;
  const size_t Rb = (size_t)blockIdx.x * 16;

  {
    int row = t >> 4, col = (t & 15) * 8;
    float4 v0 = *(const float4*)(x + (Rb + row) * F_ + col);
    float4 v1 = *(const float4*)(x + (Rb + row) * F_ + col + 4);
    uint4 pk = { pk2bf(v0.x, v0.y), pk2bf(v0.z, v0.w),
                 pk2bf(v1.x, v1.y), pk2bf(v1.z, v1.w) };
    *(uint4*)((char*)xb + row * 272 + col * 2) = pk;
  }
  __syncthreads();

  short8 bx[4];   // activation rows (B operand after swap)
  const char* ap = (const char*)xb + c16 * 272 + q * 16;
  #pragma unroll
  for (int s = 0; s < 4; ++s) bx[s] = *(const short8*)(ap + s * 64);

  #pragma unroll
  for (int u = 0; u < 2; ++u) {
    int ntile = w * 2 + u;
    const char* bb = (const char*)Wvt + (ntile * 16 + c16) * 256 + q * 16;
    floatx4 acc = {0.f, 0.f, 0.f, 0.f};
    #pragma unroll
    for (int s = 0; s < 4; ++s) {
      short8 wf = *(const short8*)(bb + s * 64);
      acc = __builtin_amdgcn_mfma_f32_16x16x32_bf16(wf, bx[s], acc, 0, 0, 0);
    }
    // D: row = c16, n = ntile*16 + q*4 + r  -> contiguous float4
    *(floatx4*)(Vo + (Rb + c16) * F_ + ntile * 16 + q * 4) = acc;
  }
}

// =====================================================================
// K2a: scores — R6-verified QK + softmax VERBATIM, minus PV.
//   Writes attn_s[a][64] (lane slot = score index; 0=self, j+1=nbr j)
//   and initializes m_pre[a][f] with the self term attn0 * V[a][f].
// =====================================================================
extern "C" __global__ __launch_bounds__(256, 4)
void scores_kernel(const float* __restrict__ Q, const float* __restrict__ K,
                   const float* __restrict__ V,
                   const int* __restrict__ nbr, const int* __restrict__ pmask,
                   float* __restrict__ attn_s, float* __restrict__ m_pre)
{
  const int t = threadIdx.x;
  const int lane = t & 63, w = t >> 6;
  const int a = blockIdx.x * 4 + w;
  const int b = a >> 11, i = a & 2047;
  const size_t base_nn = (size_t)a * NN;

  int nbrv = (lane < NN) ? nbr[base_nn + lane] : 0;
  int pmv  = (lane < NN) ? pmask[base_nn + lane] : 1;

  float2 q2 = *(const float2*)(Q + (size_t)a * F_ + lane * 2);

  float s_lane = -1e30f;
  #pragma unroll
  for (int n = 0; n < NK; ++n) {
    int src = (n == 0) ? i : __shfl(nbrv, (n > 0) ? n - 1 : 0);
    float2 k2 = *(const float2*)(K + ((size_t)b * NA + src) * F_ + lane * 2);
    float p = q2.x * k2.x + q2.y * k2.y;
    #pragma unroll
    for (int o = 32; o; o >>= 1) p += __shfl_xor(p, o);
    p *= 0.08838834764831845f;
    if (n > 0 && __shfl(pmv, n - 1) == 0) p = -1e9f;
    if (lane == n) s_lane = p;
  }

  float mx = s_lane;
  #pragma unroll
  for (int o = 32; o; o >>= 1) mx = fmaxf(mx, __shfl_xor(mx, o));
  float ev = (lane < NK) ? __expf(s_lane - mx) : 0.f;
  float sum = ev;
  #pragma unroll
  for (int o = 32; o; o >>= 1) sum += __shfl_xor(sum, o);
  float attn_l = ev / sum;

  attn_s[(size_t)a * 64 + lane] = attn_l;

  // self-term init of m_pre
  float a0 = __shfl(attn_l, 0);
  float2 vi = *(const float2*)(V + ((size_t)b * NA + i) * F_ + lane * 2);
  float2 outv = { a0 * vi.x, a0 * vi.y };
  *(float2*)(m_pre + (size_t)a * F_ + lane * 2) = outv;
}

// =====================================================================
// K1+PV: filter MLP — R4-VERIFIED structure byte-identical through
//   layer 2, plus a PV epilogue: while W[row][n] is in registers,
//   accumulate attn[row]*W*V[src[row]][n] (V is L2-resident; 16 lanes
//   share each V row -> coalesced 64B). Partials go through the dead
//   h1 LDS region (16 KB, no extra LDS), reduced per (atom,f), then
//   one global atomicAdd per (atom,f) per block (<=2-way contention at
//   atom boundaries). Eliminates attn's 100 MB Wg HBM re-read and the
//   whole PV phase. out_W still written (required output).
// =====================================================================
struct __align__(16) SmemF2 {
  union {
    ushort ft[128 * 72];    // staging: [row][72], cols 0..63 valid (50 real + pad)
    ushort h1[128 * 136];   // layer1 out: [row][136], 272 B stride
    float  pv[32 * 128];    // PV partials: [rowgroup][f] (h1 dead by then)
  } u;
  float C[128];
};  // 35328 B

extern "C" __global__ __launch_bounds__(256, 4)
void filter_pv_kernel(const float* __restrict__ fij, const float* __restrict__ r_ij,
                      const ushort* __restrict__ Wf1t, const float* __restrict__ bf1,
                      const ushort* __restrict__ Wf2t, const float* __restrict__ bf2p,
                      const float* __restrict__ V, const float* __restrict__ attn_s,
                      const int* __restrict__ nbr,
                      float* __restrict__ out_W, float* __restrict__ m_pre)
{
  __shared__ SmemF2 sm;
  const int t = threadIdx.x;
  const int lane = t & 63, w = t >> 6;
  const int c16 = lane & 15, q = lane >> 4;
  const int m0 = w * 32;                 // wave's first row (2 m-tiles of 16)
  const size_t Rb = (size_t)blockIdx.x * 128;

  // ---- stage f_ij -> bf16 LDS [128][72] as 2*f-1 ----
  #pragma unroll
  for (int it = 0; it < 16; ++it) {
    int idx = t + it * 256;              // 4096 = 128 rows * 32 uint slots
    int row = idx >> 5, kp = idx & 31;
    uint pk = 0;
    if (kp < 25) {
      float2 v = *(const float2*)(fij + (Rb + row) * G_ + 2 * kp);
      pk = pk2bf(2.f * v.x - 1.f, 2.f * v.y - 1.f);
    }
    ((uint*)sm.u.ft)[row * 36 + kp] = pk;
  }
  if (t < 128) {
    float r = r_ij[Rb + t];
    sm.C[t] = (r < 5.0f) ? 0.5f * (cosf(0.62831853071795864769f * r) + 1.0f) : 0.0f;
  }
  __syncthreads();

  // ---- preload layer1 A-fragments for own 32 rows (16 VGPR) ----
  short8 a1[2][2];
  #pragma unroll
  for (int mt = 0; mt < 2; ++mt) {
    const char* ap = (const char*)sm.u.ft + (m0 + mt * 16 + c16) * 144 + q * 16;
    a1[mt][0] = *(const short8*)(ap);
    a1[mt][1] = *(const short8*)(ap + 64);
  }
  __syncthreads();   // all waves done with ft; LDS region becomes h1

  // ---- preload ALL layer1 B-fragments (whole Wf1t, 64 VGPR) ----
  short8 b1[8][2];
  #pragma unroll
  for (int nt = 0; nt < 8; ++nt) {
    const char* bb = (const char*)Wf1t + (nt * 16 + c16) * 128 + q * 16;
    b1[nt][0] = *(const short8*)(bb);
    b1[nt][1] = *(const short8*)(bb + 64);
  }

  // ---- layer1: M=32 N=128 K=64, ssp -> h1 (own rows; no barrier) ----
  #pragma unroll
  for (int nt = 0; nt < 8; ++nt) {
    int n = nt * 16 + c16;
    float bias = bf1[n];
    #pragma unroll
    for (int mt = 0; mt < 2; ++mt) {
      floatx4 acc = {0.f, 0.f, 0.f, 0.f};
      acc = __builtin_amdgcn_mfma_f32_16x16x32_bf16(a1[mt][0], b1[nt][0], acc, 0, 0, 0);
      acc = __builtin_amdgcn_mfma_f32_16x16x32_bf16(a1[mt][1], b1[nt][1], acc, 0, 0, 0);
      #pragma unroll
      for (int r = 0; r < 4; ++r) {
        int row = m0 + mt * 16 + q * 4 + r;
        sm.u.h1[row * 136 + n] = f2bf(ssp(acc[r] + bias));
      }
    }
  }

  // ---- layer2 A-fragments from own h1 rows (32 VGPR) ----
  short8 a2[2][4];
  #pragma unroll
  for (int mt = 0; mt < 2; ++mt) {
    const char* ap = (const char*)sm.u.h1 + (m0 + mt * 16 + c16) * 272 + q * 16;
    #pragma unroll
    for (int s = 0; s < 4; ++s) a2[mt][s] = *(const short8*)(ap + s * 64);
  }
  __syncthreads();   // a2 reads done everywhere; u region becomes PV partials

  // ---- per-row attn weight + V row index (8 rows/thread) ----
  float attw[2][4]; int vrow[2][4];
  #pragma unroll
  for (int mt = 0; mt < 2; ++mt) {
    #pragma unroll
    for (int r = 0; r < 4; ++r) {
      int row = m0 + mt * 16 + q * 4 + r;
      size_t p = Rb + row;
      int ag = (int)(p / 48), j = (int)(p % 48);
      attw[mt][r] = attn_s[(size_t)ag * 64 + j + 1];
      vrow[mt][r] = (ag >> 11) * NA + nbr[p];
    }
  }

  // ---- layer2: M=32 N=128 K=128, + fused PV partial accumulation ----
  #pragma unroll
  for (int g = 0; g < 2; ++g) {
    short8 b2[4][4];
    #pragma unroll
    for (int j = 0; j < 4; ++j) {
      int n = (g * 4 + j) * 16 + c16;
      const char* bb = (const char*)Wf2t + n * 256 + q * 16;
      #pragma unroll
      for (int s = 0; s < 4; ++s) b2[j][s] = *(const short8*)(bb + s * 64);
    }
    #pragma unroll
    for (int j = 0; j < 4; ++j) {
      int n = (g * 4 + j) * 16 + c16;
      float bias = bf2p[n];
      #pragma unroll
      for (int mt = 0; mt < 2; ++mt) {
        floatx4 acc = {0.f, 0.f, 0.f, 0.f};
        #pragma unroll
        for (int s = 0; s < 4; ++s)
          acc = __builtin_amdgcn_mfma_f32_16x16x32_bf16(a2[mt][s], b2[j][s], acc, 0, 0, 0);
        float s_pv = 0.f;
        #pragma unroll
        for (int r = 0; r < 4; ++r) {
          int row = m0 + mt * 16 + q * 4 + r;
          float wv = (acc[r] + bias) * sm.C[row];
          out_W[(Rb + row) * F_ + n] = wv;
          float vv = V[(size_t)vrow[mt][r] * F_ + n];
          s_pv += attw[mt][r] * wv * vv;
        }
        int rg = (w << 3) + (mt << 2) + q;     // rowgroup 0..31
        sm.u.pv[rg * 128 + n] = s_pv;
      }
    }
  }
  __syncthreads();

  // ---- reduce rowgroups per (atom, f); one atomicAdd per output ----
  const int agmin = (int)(Rb / 48);
  const int agmax = (int)((Rb + 127) / 48);
  const int nout = (agmax - agmin + 1) * 128;
  for (int o = t; o < nout; o += 256) {
    int ag = agmin + (o >> 7), f = o & 127;
    float ssum = 0.f;
    #pragma unroll
    for (int rg = 0; rg < 32; ++rg) {
      int a_of = (int)((Rb + rg * 4) / 48);
      if (a_of == ag) ssum += sm.u.pv[rg * 128 + f];
    }
    atomicAdd(&m_pre[(size_t)ag * F_ + f], ssum);
  }
}

// =====================================================================
// K3: out_m = ssp(m_pre @ Wo + bo) via MFMA — operand-swapped stores.
//     (R2-verified, kept.)
// =====================================================================
extern "C" __global__ __launch_bounds__(256, 4)
void out_kernel(const float* __restrict__ m_pre, const ushort* __restrict__ Wot,
                const float* __restrict__ bo, float* __restrict__ out_m)
{
  __shared__ ushort xb[16 * 136];
  const int t = threadIdx.x;
  const int lane = t & 63, w = t >> 6;
  const int c16 = lane & 15, q = lane >> 4;
  const size_t Rb = (size_t)blockIdx.x * 16;

  {
    int row = t >> 4, col = (t & 15) * 8;
    float4 v0 = *(const float4*)(m_pre + (Rb + row) * F_ + col);
    float4 v1 = *(const float4*)(m_pre + (Rb + row) * F_ + col + 4);
    uint4 pk = { pk2bf(v0.x, v0.y), pk2bf(v0.z, v0.w),
                 pk2bf(v1.x, v1.y), pk2bf(v1.z, v1.w) };
    *(uint4*)((char*)xb + row * 272 + col * 2) = pk;
  }
  __syncthreads();

  short8 bx[4];
  const char* ap = (const char*)xb + c16 * 272 + q * 16;
  #pragma unroll
  for (int s = 0; s < 4; ++s) bx[s] = *(const short8*)(ap + s * 64);

  #pragma unroll
  for (int u = 0; u < 2; ++u) {
    int ntile = w * 2 + u;
    const char* bb = (const char*)Wot + (ntile * 16 + c16) * 256 + q * 16;
    floatx4 acc = {0.f, 0.f, 0.f, 0.f};
    #pragma unroll
    for (int s = 0; s < 4; ++s) {
      short8 wf = *(const short8*)(bb + s * 64);
      acc = __builtin_amdgcn_mfma_f32_16x16x32_bf16(wf, bx[s], acc, 0, 0, 0);
    }
    int n0 = ntile * 16 + q * 4;
    float4 bv = *(const float4*)&bo[n0];
    floatx4 outv;
    outv[0] = ssp(acc[0] + bv.x);
    outv[1] = ssp(acc[1] + bv.y);
    outv[2] = ssp(acc[2] + bv.z);
    outv[3] = ssp(acc[3] + bv.w);
    *(floatx4*)(out_m + (Rb + c16) * F_ + n0) = outv;
  }
}

extern "C" void kernel_launch(void* const* d_in, const int* in_sizes, int n_in,
                              void* d_out, int out_size, void* d_ws, size_t ws_size,
                              hipStream_t stream) {
  // inputs: 0=e(unused) 1=x 2=t(unused) 3=r_ij 4=neighbors 5=pairwise_mask 6=f_ij
  //         7=Wf1 8=bf1 9=Wf2 10=bf2 11=Wq 12=Wk 13=Wv 14=Wo 15=bo
  const float* x   = (const float*)d_in[1];
  const float* r   = (const float*)d_in[3];
  const int*  nbr  = (const int*)d_in[4];
  const int*  pmk  = (const int*)d_in[5];
  const float* fij = (const float*)d_in[6];
  const float* Wf1 = (const float*)d_in[7];
  const float* bf1 = (const float*)d_in[8];
  const float* Wf2 = (const float*)d_in[9];
  const float* bf2p= (const float*)d_in[10];
  const float* Wq  = (const float*)d_in[11];
  const float* Wk  = (const float*)d_in[12];
  const float* Wv  = (const float*)d_in[13];
  const float* Wo  = (const float*)d_in[14];
  const float* bo  = (const float*)d_in[15];
  float* out_m = (float*)d_out;                       // [B,Na,F]
  float* out_W = out_m + (size_t)NAT * F_;            // [B,Na,Nn,F]

  // ws: Q|K|V|m_pre (4x2MB f32) | Wf1t | Wf2t | Wvt | Wot (bf16) | attn_s (1MB f32)
  float* Qs = (float*)d_ws;
  float* Ks = Qs + (size_t)NAT * F_;
  float* Vs = Ks + (size_t)NAT * F_;
  float* Ms = Vs + (size_t)NAT * F_;
  ushort* Wf1t = (ushort*)(Ms + (size_t)NAT * F_);
  ushort* Wf2t = Wf1t + 128 * 64;
  ushort* Wvt  = Wf2t + 128 * 128;
  ushort* Wot  = Wvt  + 128 * 128;
  float* As    = (float*)(Wot + 128 * 128);           // attn_s [NAT][64]

  hipLaunchKernelGGL(prep_kernel, dim3(96), dim3(256), 0, stream,
                     Wf1, Wf2, Wv, Wo, Wf1t, Wf2t, Wvt, Wot);
  hipLaunchKernelGGL(qk_kernel, dim3(NAT / 32, 2), dim3(256), 0, stream,
                     x, Wq, Wk, Qs, Ks);
  hipLaunchKernelGGL(v_kernel, dim3(NAT / 16), dim3(256), 0, stream,
                     x, Wvt, Vs);
  hipLaunchKernelGGL(scores_kernel, dim3(NAT / 4), dim3(256), 0, stream,
                     Qs, Ks, Vs, nbr, pmk, As, Ms);
  hipLaunchKernelGGL(filter_pv_kernel, dim3(NROW / 128), dim3(256), 0, stream,
                     fij, r, Wf1t, bf1, Wf2t, bf2p, Vs, As, nbr, out_W, Ms);
  hipLaunchKernelGGL(out_kernel, dim3(NAT / 16), dim3(256), 0, stream,
                     Ms, Wot, bo, out_m);
}

// Round 10
// 268.673 us; speedup vs baseline: 1.2201x; 1.2201x over previous
//
#include <hip/hip_runtime.h>

typedef unsigned int uint;
typedef unsigned short ushort;

#define B_  2
#define NA  2048
#define NN  48
#define G_  50
#define F_  128
#define NK  49   // Nn + 1 (self)
#define NROW (B_ * NA * NN)   // 196608 flat filter rows
#define NAT  (B_ * NA)        // 4096 atoms

typedef short short8 __attribute__((ext_vector_type(8)));
typedef float floatx4 __attribute__((ext_vector_type(4)));

__device__ __forceinline__ float ssp(float z) {  // softplus(z)-ln2: fast v_exp/v_log
  return fmaxf(z, 0.f) + __logf(1.f + __expf(-fabsf(z))) - 0.69314718055994531f;
}
__device__ __forceinline__ ushort f2bf(float x) {  // RNE
  union { float f; uint u; } v; v.f = x;
  uint u = v.u;
  u += 0x7fffu + ((u >> 16) & 1u);
  return (ushort)(u >> 16);
}
__device__ __forceinline__ uint pk2bf(float x, float y) {
  return (uint)f2bf(x) | ((uint)f2bf(y) << 16);
}

// =====================================================================
// P: weight prep -> transposed bf16 [n][k] tables (MFMA B-fragments)
//    for filter (Wf1,Wf2), V and O paths. Q/K stay f32.
// =====================================================================
extern "C" __global__ __launch_bounds__(256)
void prep_kernel(const float* __restrict__ Wf1, const float* __restrict__ Wf2,
                 const float* __restrict__ Wv, const float* __restrict__ Wo,
                 ushort* __restrict__ Wf1t, ushort* __restrict__ Wf2t,
                 ushort* __restrict__ Wvt, ushort* __restrict__ Wot)
{
  int gid = blockIdx.x * 256 + threadIdx.x;   // 24576 threads
  if (gid < 8192) {   // Wf1t [128][64], K padded 50->64
    int n = gid >> 6, k = gid & 63;
    Wf1t[gid] = f2bf((k < G_) ? Wf1[(size_t)k * F_ + n] : 0.f);
  }
  for (int idx = gid; idx < 3 * 16384; idx += 24576) {
    int m = idx >> 14, e = idx & 16383;
    int n = e >> 7, k = e & 127;
    const float* src = (m == 0) ? Wf2 : (m == 1) ? Wv : Wo;
    ushort* dst = (m == 0) ? Wf2t : (m == 1) ? Wvt : Wot;
    dst[e] = f2bf(src[(size_t)k * F_ + n]);
  }
}

// =====================================================================
// K0 MERGED: qk (blocks 0..255, R5/R6-proven body verbatim, grid
//   flattened from (128,2)) + v (blocks 256..511, R2-verified body
//   verbatim). The two are independent (v needs only prep's Wvt);
//   merging runs them concurrently: 512 blocks = 2/CU instead of two
//   serial 1-block/CU launches, halving exposed latency + one less gap.
// =====================================================================
union SmemQV {
  float  xs[32 * 128];   // qk staging (16 KB)
  ushort xb[16 * 136];   // v staging (4.25 KB)
};

extern "C" __global__ __launch_bounds__(256, 4)
void qv_kernel(const float* __restrict__ x,
               const float* __restrict__ Wq, const float* __restrict__ Wk,
               const ushort* __restrict__ Wvt,
               float* __restrict__ Qo, float* __restrict__ Ko,
               float* __restrict__ Vo)
{
  __shared__ SmemQV sm;
  const int t = threadIdx.x;

  if (blockIdx.x < 256) {
    // ---------------- qk part (verbatim, grid remap) ----------------
    const int part = blockIdx.x;           // was dim3(128, 2)
    const int f = t & 127, h = t >> 7;
    const size_t Rb = (size_t)(part & 127) * 32;
    const int yb = part >> 7;
    const float* W = yb ? Wk : Wq;
    float* O = yb ? Ko : Qo;

    {
      const float4* src = (const float4*)(x + Rb * F_);
      float4* dst = (float4*)sm.xs;
      #pragma unroll
      for (int k = 0; k < 4; ++k) dst[t + 256 * k] = src[t + 256 * k];
    }
    __syncthreads();

    float acc[16];
    #pragma unroll
    for (int j = 0; j < 16; ++j) acc[j] = 0.f;
    #pragma unroll
    for (int kc = 0; kc < 4; ++kc) {
      float wr[32];
      #pragma unroll
      for (int kk = 0; kk < 32; ++kk) wr[kk] = W[(size_t)(kc * 32 + kk) * F_ + f];
      #pragma unroll
      for (int j = 0; j < 16; ++j) {
        const float4* xr = (const float4*)&sm.xs[(h * 16 + j) * 128 + kc * 32];
        #pragma unroll
        for (int qq = 0; qq < 8; ++qq) {   // wave-uniform b128 broadcasts
          float4 v = xr[qq];
          acc[j] += v.x * wr[qq * 4] + v.y * wr[qq * 4 + 1]
                  + v.z * wr[qq * 4 + 2] + v.w * wr[qq * 4 + 3];
        }
      }
    }
    #pragma unroll
    for (int j = 0; j < 16; ++j)
      O[(Rb + h * 16 + j) * F_ + f] = acc[j];
  } else {
    // ---------------- v part (verbatim, grid remap) ----------------
    const int vb = blockIdx.x - 256;
    const int lane = t & 63, w = t >> 6;
    const int c16 = lane & 15, q = lane >> 4;
    const size_t Rb = (size_t)vb * 16;

    {
      int row = t >> 4, col = (t & 15) * 8;
      float4 v0 = *(const float4*)(x + (Rb + row) * F_ + col);
      float4 v1 = *(const float4*)(x + (Rb + row) * F_ + col + 4);
      uint4 pk = { pk2bf(v0.x, v0.y), pk2bf(v0.z, v0.w),
                   pk2bf(v1.x, v1.y), pk2bf(v1.z, v1.w) };
      *(uint4*)((char*)sm.xb + row * 272 + col * 2) = pk;
    }
    __syncthreads();

    short8 bx[4];   // activation rows (B operand after swap)
    const char* ap = (const char*)sm.xb + c16 * 272 + q * 16;
    #pragma unroll
    for (int s = 0; s < 4; ++s) bx[s] = *(const short8*)(ap + s * 64);

    #pragma unroll
    for (int u = 0; u < 2; ++u) {
      int ntile = w * 2 + u;
      const char* bb = (const char*)Wvt + (ntile * 16 + c16) * 256 + q * 16;
      floatx4 acc = {0.f, 0.f, 0.f, 0.f};
      #pragma unroll
      for (int s = 0; s < 4; ++s) {
        short8 wf = *(const short8*)(bb + s * 64);
        acc = __builtin_amdgcn_mfma_f32_16x16x32_bf16(wf, bx[s], acc, 0, 0, 0);
      }
      // D: row = c16, n = ntile*16 + q*4 + r  -> contiguous float4
      *(floatx4*)(Vo + (Rb + c16) * F_ + ntile * 16 + q * 4) = acc;
    }
  }
}

// =====================================================================
// K1: filter MLP via bf16 MFMA — R4-VERIFIED 128-row/32-rows-per-wave
//     version VERBATIM (81-82 us, session best for this kernel).
// =====================================================================
struct __align__(16) SmemF2 {
  union {
    ushort ft[128 * 72];    // staging: [row][72], cols 0..63 valid (50 real + pad)
    ushort h1[128 * 136];   // layer1 out: [row][136], 272 B stride
  } u;
  float C[128];
};  // 35328 B

extern "C" __global__ __launch_bounds__(256, 4)
void filter_kernel(const float* __restrict__ fij, const float* __restrict__ r_ij,
                   const ushort* __restrict__ Wf1t, const float* __restrict__ bf1,
                   const ushort* __restrict__ Wf2t, const float* __restrict__ bf2p,
                   float* __restrict__ out_W)
{
  __shared__ SmemF2 sm;
  const int t = threadIdx.x;
  const int lane = t & 63, w = t >> 6;
  const int c16 = lane & 15, q = lane >> 4;
  const int m0 = w * 32;                 // wave's first row (2 m-tiles of 16)
  const size_t Rb = (size_t)blockIdx.x * 128;

  // ---- stage f_ij -> bf16 LDS [128][72] as 2*f-1 ----
  #pragma unroll
  for (int it = 0; it < 16; ++it) {
    int idx = t + it * 256;              // 4096 = 128 rows * 32 uint slots
    int row = idx >> 5, kp = idx & 31;
    uint pk = 0;
    if (kp < 25) {
      float2 v = *(const float2*)(fij + (Rb + row) * G_ + 2 * kp);
      pk = pk2bf(2.f * v.x - 1.f, 2.f * v.y - 1.f);
    }
    ((uint*)sm.u.ft)[row * 36 + kp] = pk;
  }
  if (t < 128) {
    float r = r_ij[Rb + t];
    sm.C[t] = (r < 5.0f) ? 0.5f * (cosf(0.62831853071795864769f * r) + 1.0f) : 0.0f;
  }
  __syncthreads();

  // ---- preload layer1 A-fragments for own 32 rows (16 VGPR) ----
  short8 a1[2][2];
  #pragma unroll
  for (int mt = 0; mt < 2; ++mt) {
    const char* ap = (const char*)sm.u.ft + (m0 + mt * 16 + c16) * 144 + q * 16;
    a1[mt][0] = *(const short8*)(ap);
    a1[mt][1] = *(const short8*)(ap + 64);
  }
  __syncthreads();   // all waves done with ft; LDS region becomes h1

  // ---- preload ALL layer1 B-fragments (whole Wf1t, 64 VGPR) ----
  short8 b1[8][2];
  #pragma unroll
  for (int nt = 0; nt < 8; ++nt) {
    const char* bb = (const char*)Wf1t + (nt * 16 + c16) * 128 + q * 16;
    b1[nt][0] = *(const short8*)(bb);
    b1[nt][1] = *(const short8*)(bb + 64);
  }

  // ---- layer1: M=32 N=128 K=64, ssp -> h1 (own rows; no barrier) ----
  #pragma unroll
  for (int nt = 0; nt < 8; ++nt) {
    int n = nt * 16 + c16;
    float bias = bf1[n];
    #pragma unroll
    for (int mt = 0; mt < 2; ++mt) {
      floatx4 acc = {0.f, 0.f, 0.f, 0.f};
      acc = __builtin_amdgcn_mfma_f32_16x16x32_bf16(a1[mt][0], b1[nt][0], acc, 0, 0, 0);
      acc = __builtin_amdgcn_mfma_f32_16x16x32_bf16(a1[mt][1], b1[nt][1], acc, 0, 0, 0);
      #pragma unroll
      for (int r = 0; r < 4; ++r) {
        int row = m0 + mt * 16 + q * 4 + r;
        sm.u.h1[row * 136 + n] = f2bf(ssp(acc[r] + bias));
      }
    }
  }

  // ---- layer2 A-fragments from own h1 rows (32 VGPR) ----
  short8 a2[2][4];
  #pragma unroll
  for (int mt = 0; mt < 2; ++mt) {
    const char* ap = (const char*)sm.u.h1 + (m0 + mt * 16 + c16) * 272 + q * 16;
    #pragma unroll
    for (int s = 0; s < 4; ++s) a2[mt][s] = *(const short8*)(ap + s * 64);
  }

  // ---- layer2: M=32 N=128 K=128, B in 2 register groups of 16 frags ----
  #pragma unroll
  for (int g = 0; g < 2; ++g) {
    short8 b2[4][4];
    #pragma unroll
    for (int j = 0; j < 4; ++j) {
      int n = (g * 4 + j) * 16 + c16;
      const char* bb = (const char*)Wf2t + n * 256 + q * 16;
      #pragma unroll
      for (int s = 0; s < 4; ++s) b2[j][s] = *(const short8*)(bb + s * 64);
    }
    #pragma unroll
    for (int j = 0; j < 4; ++j) {
      int n = (g * 4 + j) * 16 + c16;
      float bias = bf2p[n];
      #pragma unroll
      for (int mt = 0; mt < 2; ++mt) {
        floatx4 acc = {0.f, 0.f, 0.f, 0.f};
        #pragma unroll
        for (int s = 0; s < 4; ++s)
          acc = __builtin_amdgcn_mfma_f32_16x16x32_bf16(a2[mt][s], b2[j][s], acc, 0, 0, 0);
        #pragma unroll
        for (int r = 0; r < 4; ++r) {
          int row = m0 + mt * 16 + q * 4 + r;
          out_W[(Rb + row) * F_ + n] = (acc[r] + bias) * sm.C[row];
        }
      }
    }
  }
}

// =====================================================================
// K2: wave-per-atom attention — R6-VERIFIED version, VERBATIM.
//   (R9 showed the PV phase incl. the Wg re-read is ~3 us — out_W is
//    L3-resident. attn is QK-phase-dominated; keep the proven code.)
// =====================================================================
extern "C" __global__ __launch_bounds__(256, 4)
void attn_kernel(const float* __restrict__ Q, const float* __restrict__ K,
                 const float* __restrict__ V, const float* __restrict__ Wg,
                 const int* __restrict__ nbr, const int* __restrict__ pmask,
                 float* __restrict__ m_pre)
{
  const int t = threadIdx.x;
  const int lane = t & 63, w = t >> 6;
  const int a = blockIdx.x * 4 + w;
  const int b = a >> 11, i = a & 2047;
  const size_t base_nn = (size_t)a * NN;

  int nbrv = (lane < NN) ? nbr[base_nn + lane] : 0;
  int pmv  = (lane < NN) ? pmask[base_nn + lane] : 1;

  float2 q2 = *(const float2*)(Q + (size_t)a * F_ + lane * 2);

  float s_lane = -1e30f;
  #pragma unroll
  for (int n = 0; n < NK; ++n) {
    int src = (n == 0) ? i : __shfl(nbrv, (n > 0) ? n - 1 : 0);
    float2 k2 = *(const float2*)(K + ((size_t)b * NA + src) * F_ + lane * 2);
    float p = q2.x * k2.x + q2.y * k2.y;
    #pragma unroll
    for (int o = 32; o; o >>= 1) p += __shfl_xor(p, o);
    p *= 0.08838834764831845f;
    if (n > 0 && __shfl(pmv, n - 1) == 0) p = -1e9f;
    if (lane == n) s_lane = p;
  }

  float mx = s_lane;
  #pragma unroll
  for (int o = 32; o; o >>= 1) mx = fmaxf(mx, __shfl_xor(mx, o));
  float ev = (lane < NK) ? __expf(s_lane - mx) : 0.f;
  float sum = ev;
  #pragma unroll
  for (int o = 32; o; o >>= 1) sum += __shfl_xor(sum, o);
  float attn_l = ev / sum;

  float2 acc = {0.f, 0.f};
  #pragma unroll 8
  for (int n = 0; n < NK; ++n) {
    float an = __shfl(attn_l, n);
    int src = (n == 0) ? i : __shfl(nbrv, (n > 0) ? n - 1 : 0);
    float2 v2 = *(const float2*)(V + ((size_t)b * NA + src) * F_ + lane * 2);
    float2 w2 = {1.f, 1.f};
    if (n > 0) w2 = *(const float2*)(Wg + (base_nn + n - 1) * F_ + lane * 2);
    acc.x += an * w2.x * v2.x;
    acc.y += an * w2.y * v2.y;
  }
  *(float2*)(m_pre + (size_t)a * F_ + lane * 2) = acc;
}

// =====================================================================
// K3: out_m = ssp(m_pre @ Wo + bo) via MFMA — operand-swapped stores.
//     (R2-verified, kept.)
// =====================================================================
extern "C" __global__ __launch_bounds__(256, 4)
void out_kernel(const float* __restrict__ m_pre, const ushort* __restrict__ Wot,
                const float* __restrict__ bo, float* __restrict__ out_m)
{
  __shared__ ushort xb[16 * 136];
  const int t = threadIdx.x;
  const int lane = t & 63, w = t >> 6;
  const int c16 = lane & 15, q = lane >> 4;
  const size_t Rb = (size_t)blockIdx.x * 16;

  {
    int row = t >> 4, col = (t & 15) * 8;
    float4 v0 = *(const float4*)(m_pre + (Rb + row) * F_ + col);
    float4 v1 = *(const float4*)(m_pre + (Rb + row) * F_ + col + 4);
    uint4 pk = { pk2bf(v0.x, v0.y), pk2bf(v0.z, v0.w),
                 pk2bf(v1.x, v1.y), pk2bf(v1.z, v1.w) };
    *(uint4*)((char*)xb + row * 272 + col * 2) = pk;
  }
  __syncthreads();

  short8 bx[4];
  const char* ap = (const char*)xb + c16 * 272 + q * 16;
  #pragma unroll
  for (int s = 0; s < 4; ++s) bx[s] = *(const short8*)(ap + s * 64);

  #pragma unroll
  for (int u = 0; u < 2; ++u) {
    int ntile = w * 2 + u;
    const char* bb = (const char*)Wot + (ntile * 16 + c16) * 256 + q * 16;
    floatx4 acc = {0.f, 0.f, 0.f, 0.f};
    #pragma unroll
    for (int s = 0; s < 4; ++s) {
      short8 wf = *(const short8*)(bb + s * 64);
      acc = __builtin_amdgcn_mfma_f32_16x16x32_bf16(wf, bx[s], acc, 0, 0, 0);
    }
    int n0 = ntile * 16 + q * 4;
    float4 bv = *(const float4*)&bo[n0];
    floatx4 outv;
    outv[0] = ssp(acc[0] + bv.x);
    outv[1] = ssp(acc[1] + bv.y);
    outv[2] = ssp(acc[2] + bv.z);
    outv[3] = ssp(acc[3] + bv.w);
    *(floatx4*)(out_m + (Rb + c16) * F_ + n0) = outv;
  }
}

extern "C" void kernel_launch(void* const* d_in, const int* in_sizes, int n_in,
                              void* d_out, int out_size, void* d_ws, size_t ws_size,
                              hipStream_t stream) {
  // inputs: 0=e(unused) 1=x 2=t(unused) 3=r_ij 4=neighbors 5=pairwise_mask 6=f_ij
  //         7=Wf1 8=bf1 9=Wf2 10=bf2 11=Wq 12=Wk 13=Wv 14=Wo 15=bo
  const float* x   = (const float*)d_in[1];
  const float* r   = (const float*)d_in[3];
  const int*  nbr  = (const int*)d_in[4];
  const int*  pmk  = (const int*)d_in[5];
  const float* fij = (const float*)d_in[6];
  const float* Wf1 = (const float*)d_in[7];
  const float* bf1 = (const float*)d_in[8];
  const float* Wf2 = (const float*)d_in[9];
  const float* bf2p= (const float*)d_in[10];
  const float* Wq  = (const float*)d_in[11];
  const float* Wk  = (const float*)d_in[12];
  const float* Wv  = (const float*)d_in[13];
  const float* Wo  = (const float*)d_in[14];
  const float* bo  = (const float*)d_in[15];
  float* out_m = (float*)d_out;                       // [B,Na,F]
  float* out_W = out_m + (size_t)NAT * F_;            // [B,Na,Nn,F]

  // ws: Q|K|V|m_pre (4x2MB f32) | Wf1t | Wf2t | Wvt | Wot (bf16)
  float* Qs = (float*)d_ws;
  float* Ks = Qs + (size_t)NAT * F_;
  float* Vs = Ks + (size_t)NAT * F_;
  float* Ms = Vs + (size_t)NAT * F_;
  ushort* Wf1t = (ushort*)(Ms + (size_t)NAT * F_);
  ushort* Wf2t = Wf1t + 128 * 64;
  ushort* Wvt  = Wf2t + 128 * 128;
  ushort* Wot  = Wvt  + 128 * 128;

  hipLaunchKernelGGL(prep_kernel, dim3(96), dim3(256), 0, stream,
                     Wf1, Wf2, Wv, Wo, Wf1t, Wf2t, Wvt, Wot);
  hipLaunchKernelGGL(qv_kernel, dim3(512), dim3(256), 0, stream,
                     x, Wq, Wk, Wvt, Qs, Ks, Vs);
  hipLaunchKernelGGL(filter_kernel, dim3(NROW / 128), dim3(256), 0, stream,
                     fij, r, Wf1t, bf1, Wf2t, bf2p, out_W);
  hipLaunchKernelGGL(attn_kernel, dim3(NAT / 4), dim3(256), 0, stream,
                     Qs, Ks, Vs, out_W, nbr, pmk, Ms);
  hipLaunchKernelGGL(out_kernel, dim3(NAT / 16), dim3(256), 0, stream,
                     Ms, Wot, bo, out_m);
}

// Round 11
// 257.866 us; speedup vs baseline: 1.2713x; 1.0419x over previous
//
#include <hip/hip_runtime.h>

typedef unsigned int uint;
typedef unsigned short ushort;

#define B_  2
#define NA  2048
#define NN  48
#define G_  50
#define F_  128
#define NK  49   // Nn + 1 (self)
#define NROW (B_ * NA * NN)   // 196608 flat filter rows
#define NAT  (B_ * NA)        // 4096 atoms

typedef short short8 __attribute__((ext_vector_type(8)));
typedef float floatx4 __attribute__((ext_vector_type(4)));

__device__ __forceinline__ float ssp(float z) {  // softplus(z)-ln2: fast v_exp/v_log
  return fmaxf(z, 0.f) + __logf(1.f + __expf(-fabsf(z))) - 0.69314718055994531f;
}
__device__ __forceinline__ ushort f2bf(float x) {  // RNE
  union { float f; uint u; } v; v.f = x;
  uint u = v.u;
  u += 0x7fffu + ((u >> 16) & 1u);
  return (ushort)(u >> 16);
}
__device__ __forceinline__ uint pk2bf(float x, float y) {
  return (uint)f2bf(x) | ((uint)f2bf(y) << 16);
}

// =====================================================================
// P: weight prep -> transposed bf16 [n][k] tables (MFMA B-fragments)
//    for filter (Wf1,Wf2), V and O paths. Q/K stay f32.
// =====================================================================
extern "C" __global__ __launch_bounds__(256)
void prep_kernel(const float* __restrict__ Wf1, const float* __restrict__ Wf2,
                 const float* __restrict__ Wv, const float* __restrict__ Wo,
                 ushort* __restrict__ Wf1t, ushort* __restrict__ Wf2t,
                 ushort* __restrict__ Wvt, ushort* __restrict__ Wot)
{
  int gid = blockIdx.x * 256 + threadIdx.x;   // 24576 threads
  if (gid < 8192) {   // Wf1t [128][64], K padded 50->64
    int n = gid >> 6, k = gid & 63;
    Wf1t[gid] = f2bf((k < G_) ? Wf1[(size_t)k * F_ + n] : 0.f);
  }
  for (int idx = gid; idx < 3 * 16384; idx += 24576) {
    int m = idx >> 14, e = idx & 16383;
    int n = e >> 7, k = e & 127;
    const float* src = (m == 0) ? Wf2 : (m == 1) ? Wv : Wo;
    ushort* dst = (m == 0) ? Wf2t : (m == 1) ? Wvt : Wot;
    dst[e] = f2bf(src[(size_t)k * F_ + n]);
  }
}

// =====================================================================
// K0+K1 MERGED: qv (blocks 0..511: qk R5/R6-proven body + v R2-verified
//   body, both verbatim from the R10 qv_kernel) + filter (blocks
//   512..2047, R4-verified body verbatim). qv and filter are mutually
//   independent (qv needs Wvt+x; filter needs Wf1t/Wf2t+fij), so the
//   512 qv blocks fill the idle wave slots of the latency-bound,
//   LDS-capped filter blocks instead of running serially after it.
//   LDS = union (35.3 KB, unchanged filter footprint); bodies verbatim.
// =====================================================================
struct __align__(16) SmemM {
  union {
    struct {
      union {
        ushort ft[128 * 72];    // filter staging
        ushort h1[128 * 136];   // filter layer1 out
      } u;
      float C[128];
    } f;                        // 35328 B
    float  xs[32 * 128];        // qk staging (16 KB)
    ushort xb[16 * 136];        // v staging (4.25 KB)
  };
};

extern "C" __global__ __launch_bounds__(256, 4)
void fqv_kernel(const float* __restrict__ x,
                const float* __restrict__ Wq, const float* __restrict__ Wk,
                const ushort* __restrict__ Wvt,
                float* __restrict__ Qo, float* __restrict__ Ko,
                float* __restrict__ Vo,
                const float* __restrict__ fij, const float* __restrict__ r_ij,
                const ushort* __restrict__ Wf1t, const float* __restrict__ bf1,
                const ushort* __restrict__ Wf2t, const float* __restrict__ bf2p,
                float* __restrict__ out_W)
{
  __shared__ SmemM sm;
  const int t = threadIdx.x;
  const int bid = blockIdx.x;

  if (bid < 256) {
    // ---------------- qk part (verbatim, grid remap) ----------------
    const int part = bid;                  // was dim3(128, 2)
    const int f = t & 127, h = t >> 7;
    const size_t Rb = (size_t)(part & 127) * 32;
    const int yb = part >> 7;
    const float* W = yb ? Wk : Wq;
    float* O = yb ? Ko : Qo;

    {
      const float4* src = (const float4*)(x + Rb * F_);
      float4* dst = (float4*)sm.xs;
      #pragma unroll
      for (int k = 0; k < 4; ++k) dst[t + 256 * k] = src[t + 256 * k];
    }
    __syncthreads();

    float acc[16];
    #pragma unroll
    for (int j = 0; j < 16; ++j) acc[j] = 0.f;
    #pragma unroll
    for (int kc = 0; kc < 4; ++kc) {
      float wr[32];
      #pragma unroll
      for (int kk = 0; kk < 32; ++kk) wr[kk] = W[(size_t)(kc * 32 + kk) * F_ + f];
      #pragma unroll
      for (int j = 0; j < 16; ++j) {
        const float4* xr = (const float4*)&sm.xs[(h * 16 + j) * 128 + kc * 32];
        #pragma unroll
        for (int qq = 0; qq < 8; ++qq) {   // wave-uniform b128 broadcasts
          float4 v = xr[qq];
          acc[j] += v.x * wr[qq * 4] + v.y * wr[qq * 4 + 1]
                  + v.z * wr[qq * 4 + 2] + v.w * wr[qq * 4 + 3];
        }
      }
    }
    #pragma unroll
    for (int j = 0; j < 16; ++j)
      O[(Rb + h * 16 + j) * F_ + f] = acc[j];

  } else if (bid < 512) {
    // ---------------- v part (verbatim, grid remap) ----------------
    const int vb = bid - 256;
    const int lane = t & 63, w = t >> 6;
    const int c16 = lane & 15, q = lane >> 4;
    const size_t Rb = (size_t)vb * 16;

    {
      int row = t >> 4, col = (t & 15) * 8;
      float4 v0 = *(const float4*)(x + (Rb + row) * F_ + col);
      float4 v1 = *(const float4*)(x + (Rb + row) * F_ + col + 4);
      uint4 pk = { pk2bf(v0.x, v0.y), pk2bf(v0.z, v0.w),
                   pk2bf(v1.x, v1.y), pk2bf(v1.z, v1.w) };
      *(uint4*)((char*)sm.xb + row * 272 + col * 2) = pk;
    }
    __syncthreads();

    short8 bx[4];   // activation rows (B operand after swap)
    const char* ap = (const char*)sm.xb + c16 * 272 + q * 16;
    #pragma unroll
    for (int s = 0; s < 4; ++s) bx[s] = *(const short8*)(ap + s * 64);

    #pragma unroll
    for (int u = 0; u < 2; ++u) {
      int ntile = w * 2 + u;
      const char* bb = (const char*)Wvt + (ntile * 16 + c16) * 256 + q * 16;
      floatx4 acc = {0.f, 0.f, 0.f, 0.f};
      #pragma unroll
      for (int s = 0; s < 4; ++s) {
        short8 wf = *(const short8*)(bb + s * 64);
        acc = __builtin_amdgcn_mfma_f32_16x16x32_bf16(wf, bx[s], acc, 0, 0, 0);
      }
      // D: row = c16, n = ntile*16 + q*4 + r  -> contiguous float4
      *(floatx4*)(Vo + (Rb + c16) * F_ + ntile * 16 + q * 4) = acc;
    }

  } else {
    // ---------------- filter part (R4-verified body verbatim) ----------------
    const int lane = t & 63, w = t >> 6;
    const int c16 = lane & 15, q = lane >> 4;
    const int m0 = w * 32;                 // wave's first row (2 m-tiles of 16)
    const size_t Rb = (size_t)(bid - 512) * 128;

    // ---- stage f_ij -> bf16 LDS [128][72] as 2*f-1 ----
    #pragma unroll
    for (int it = 0; it < 16; ++it) {
      int idx = t + it * 256;              // 4096 = 128 rows * 32 uint slots
      int row = idx >> 5, kp = idx & 31;
      uint pk = 0;
      if (kp < 25) {
        float2 v = *(const float2*)(fij + (Rb + row) * G_ + 2 * kp);
        pk = pk2bf(2.f * v.x - 1.f, 2.f * v.y - 1.f);
      }
      ((uint*)sm.f.u.ft)[row * 36 + kp] = pk;
    }
    if (t < 128) {
      float r = r_ij[Rb + t];
      sm.f.C[t] = (r < 5.0f) ? 0.5f * (cosf(0.62831853071795864769f * r) + 1.0f) : 0.0f;
    }
    __syncthreads();

    // ---- preload layer1 A-fragments for own 32 rows (16 VGPR) ----
    short8 a1[2][2];
    #pragma unroll
    for (int mt = 0; mt < 2; ++mt) {
      const char* ap = (const char*)sm.f.u.ft + (m0 + mt * 16 + c16) * 144 + q * 16;
      a1[mt][0] = *(const short8*)(ap);
      a1[mt][1] = *(const short8*)(ap + 64);
    }
    __syncthreads();   // all waves done with ft; LDS region becomes h1

    // ---- preload ALL layer1 B-fragments (whole Wf1t, 64 VGPR) ----
    short8 b1[8][2];
    #pragma unroll
    for (int nt = 0; nt < 8; ++nt) {
      const char* bb = (const char*)Wf1t + (nt * 16 + c16) * 128 + q * 16;
      b1[nt][0] = *(const short8*)(bb);
      b1[nt][1] = *(const short8*)(bb + 64);
    }

    // ---- layer1: M=32 N=128 K=64, ssp -> h1 (own rows; no barrier) ----
    #pragma unroll
    for (int nt = 0; nt < 8; ++nt) {
      int n = nt * 16 + c16;
      float bias = bf1[n];
      #pragma unroll
      for (int mt = 0; mt < 2; ++mt) {
        floatx4 acc = {0.f, 0.f, 0.f, 0.f};
        acc = __builtin_amdgcn_mfma_f32_16x16x32_bf16(a1[mt][0], b1[nt][0], acc, 0, 0, 0);
        acc = __builtin_amdgcn_mfma_f32_16x16x32_bf16(a1[mt][1], b1[nt][1], acc, 0, 0, 0);
        #pragma unroll
        for (int r = 0; r < 4; ++r) {
          int row = m0 + mt * 16 + q * 4 + r;
          sm.f.u.h1[row * 136 + n] = f2bf(ssp(acc[r] + bias));
        }
      }
    }

    // ---- layer2 A-fragments from own h1 rows (32 VGPR) ----
    short8 a2[2][4];
    #pragma unroll
    for (int mt = 0; mt < 2; ++mt) {
      const char* ap = (const char*)sm.f.u.h1 + (m0 + mt * 16 + c16) * 272 + q * 16;
      #pragma unroll
      for (int s = 0; s < 4; ++s) a2[mt][s] = *(const short8*)(ap + s * 64);
    }

    // ---- layer2: M=32 N=128 K=128, B in 2 register groups of 16 frags ----
    #pragma unroll
    for (int g = 0; g < 2; ++g) {
      short8 b2[4][4];
      #pragma unroll
      for (int j = 0; j < 4; ++j) {
        int n = (g * 4 + j) * 16 + c16;
        const char* bb = (const char*)Wf2t + n * 256 + q * 16;
        #pragma unroll
        for (int s = 0; s < 4; ++s) b2[j][s] = *(const short8*)(bb + s * 64);
      }
      #pragma unroll
      for (int j = 0; j < 4; ++j) {
        int n = (g * 4 + j) * 16 + c16;
        float bias = bf2p[n];
        #pragma unroll
        for (int mt = 0; mt < 2; ++mt) {
          floatx4 acc = {0.f, 0.f, 0.f, 0.f};
          #pragma unroll
          for (int s = 0; s < 4; ++s)
            acc = __builtin_amdgcn_mfma_f32_16x16x32_bf16(a2[mt][s], b2[j][s], acc, 0, 0, 0);
          #pragma unroll
          for (int r = 0; r < 4; ++r) {
            int row = m0 + mt * 16 + q * 4 + r;
            out_W[(Rb + row) * F_ + n] = (acc[r] + bias) * sm.f.C[row];
          }
        }
      }
    }
  }
}

// =====================================================================
// K2: wave-per-atom attention — R6-VERIFIED version, VERBATIM.
// =====================================================================
extern "C" __global__ __launch_bounds__(256, 4)
void attn_kernel(const float* __restrict__ Q, const float* __restrict__ K,
                 const float* __restrict__ V, const float* __restrict__ Wg,
                 const int* __restrict__ nbr, const int* __restrict__ pmask,
                 float* __restrict__ m_pre)
{
  const int t = threadIdx.x;
  const int lane = t & 63, w = t >> 6;
  const int a = blockIdx.x * 4 + w;
  const int b = a >> 11, i = a & 2047;
  const size_t base_nn = (size_t)a * NN;

  int nbrv = (lane < NN) ? nbr[base_nn + lane] : 0;
  int pmv  = (lane < NN) ? pmask[base_nn + lane] : 1;

  float2 q2 = *(const float2*)(Q + (size_t)a * F_ + lane * 2);

  float s_lane = -1e30f;
  #pragma unroll
  for (int n = 0; n < NK; ++n) {
    int src = (n == 0) ? i : __shfl(nbrv, (n > 0) ? n - 1 : 0);
    float2 k2 = *(const float2*)(K + ((size_t)b * NA + src) * F_ + lane * 2);
    float p = q2.x * k2.x + q2.y * k2.y;
    #pragma unroll
    for (int o = 32; o; o >>= 1) p += __shfl_xor(p, o);
    p *= 0.08838834764831845f;
    if (n > 0 && __shfl(pmv, n - 1) == 0) p = -1e9f;
    if (lane == n) s_lane = p;
  }

  float mx = s_lane;
  #pragma unroll
  for (int o = 32; o; o >>= 1) mx = fmaxf(mx, __shfl_xor(mx, o));
  float ev = (lane < NK) ? __expf(s_lane - mx) : 0.f;
  float sum = ev;
  #pragma unroll
  for (int o = 32; o; o >>= 1) sum += __shfl_xor(sum, o);
  float attn_l = ev / sum;

  float2 acc = {0.f, 0.f};
  #pragma unroll 8
  for (int n = 0; n < NK; ++n) {
    float an = __shfl(attn_l, n);
    int src = (n == 0) ? i : __shfl(nbrv, (n > 0) ? n - 1 : 0);
    float2 v2 = *(const float2*)(V + ((size_t)b * NA + src) * F_ + lane * 2);
    float2 w2 = {1.f, 1.f};
    if (n > 0) w2 = *(const float2*)(Wg + (base_nn + n - 1) * F_ + lane * 2);
    acc.x += an * w2.x * v2.x;
    acc.y += an * w2.y * v2.y;
  }
  *(float2*)(m_pre + (size_t)a * F_ + lane * 2) = acc;
}

// =====================================================================
// K3: out_m = ssp(m_pre @ Wo + bo) via MFMA — operand-swapped stores.
//     (R2-verified, kept.)
// =====================================================================
extern "C" __global__ __launch_bounds__(256, 4)
void out_kernel(const float* __restrict__ m_pre, const ushort* __restrict__ Wot,
                const float* __restrict__ bo, float* __restrict__ out_m)
{
  __shared__ ushort xb[16 * 136];
  const int t = threadIdx.x;
  const int lane = t & 63, w = t >> 6;
  const int c16 = lane & 15, q = lane >> 4;
  const size_t Rb = (size_t)blockIdx.x * 16;

  {
    int row = t >> 4, col = (t & 15) * 8;
    float4 v0 = *(const float4*)(m_pre + (Rb + row) * F_ + col);
    float4 v1 = *(const float4*)(m_pre + (Rb + row) * F_ + col + 4);
    uint4 pk = { pk2bf(v0.x, v0.y), pk2bf(v0.z, v0.w),
                 pk2bf(v1.x, v1.y), pk2bf(v1.z, v1.w) };
    *(uint4*)((char*)xb + row * 272 + col * 2) = pk;
  }
  __syncthreads();

  short8 bx[4];
  const char* ap = (const char*)xb + c16 * 272 + q * 16;
  #pragma unroll
  for (int s = 0; s < 4; ++s) bx[s] = *(const short8*)(ap + s * 64);

  #pragma unroll
  for (int u = 0; u < 2; ++u) {
    int ntile = w * 2 + u;
    const char* bb = (const char*)Wot + (ntile * 16 + c16) * 256 + q * 16;
    floatx4 acc = {0.f, 0.f, 0.f, 0.f};
    #pragma unroll
    for (int s = 0; s < 4; ++s) {
      short8 wf = *(const short8*)(bb + s * 64);
      acc = __builtin_amdgcn_mfma_f32_16x16x32_bf16(wf, bx[s], acc, 0, 0, 0);
    }
    int n0 = ntile * 16 + q * 4;
    float4 bv = *(const float4*)&bo[n0];
    floatx4 outv;
    outv[0] = ssp(acc[0] + bv.x);
    outv[1] = ssp(acc[1] + bv.y);
    outv[2] = ssp(acc[2] + bv.z);
    outv[3] = ssp(acc[3] + bv.w);
    *(floatx4*)(out_m + (Rb + c16) * F_ + n0) = outv;
  }
}

extern "C" void kernel_launch(void* const* d_in, const int* in_sizes, int n_in,
                              void* d_out, int out_size, void* d_ws, size_t ws_size,
                              hipStream_t stream) {
  // inputs: 0=e(unused) 1=x 2=t(unused) 3=r_ij 4=neighbors 5=pairwise_mask 6=f_ij
  //         7=Wf1 8=bf1 9=Wf2 10=bf2 11=Wq 12=Wk 13=Wv 14=Wo 15=bo
  const float* x   = (const float*)d_in[1];
  const float* r   = (const float*)d_in[3];
  const int*  nbr  = (const int*)d_in[4];
  const int*  pmk  = (const int*)d_in[5];
  const float* fij = (const float*)d_in[6];
  const float* Wf1 = (const float*)d_in[7];
  const float* bf1 = (const float*)d_in[8];
  const float* Wf2 = (const float*)d_in[9];
  const float* bf2p= (const float*)d_in[10];
  const float* Wq  = (const float*)d_in[11];
  const float* Wk  = (const float*)d_in[12];
  const float* Wv  = (const float*)d_in[13];
  const float* Wo  = (const float*)d_in[14];
  const float* bo  = (const float*)d_in[15];
  float* out_m = (float*)d_out;                       // [B,Na,F]
  float* out_W = out_m + (size_t)NAT * F_;            // [B,Na,Nn,F]

  // ws: Q|K|V|m_pre (4x2MB f32) | Wf1t | Wf2t | Wvt | Wot (bf16)
  float* Qs = (float*)d_ws;
  float* Ks = Qs + (size_t)NAT * F_;
  float* Vs = Ks + (size_t)NAT * F_;
  float* Ms = Vs + (size_t)NAT * F_;
  ushort* Wf1t = (ushort*)(Ms + (size_t)NAT * F_);
  ushort* Wf2t = Wf1t + 128 * 64;
  ushort* Wvt  = Wf2t + 128 * 128;
  ushort* Wot  = Wvt  + 128 * 128;

  hipLaunchKernelGGL(prep_kernel, dim3(96), dim3(256), 0, stream,
                     Wf1, Wf2, Wv, Wo, Wf1t, Wf2t, Wvt, Wot);
  hipLaunchKernelGGL(fqv_kernel, dim3(512 + NROW / 128), dim3(256), 0, stream,
                     x, Wq, Wk, Wvt, Qs, Ks, Vs,
                     fij, r, Wf1t, bf1, Wf2t, bf2p, out_W);
  hipLaunchKernelGGL(attn_kernel, dim3(NAT / 4), dim3(256), 0, stream,
                     Qs, Ks, Vs, out_W, nbr, pmk, Ms);
  hipLaunchKernelGGL(out_kernel, dim3(NAT / 16), dim3(256), 0, stream,
                     Ms, Wot, bo, out_m);
}